// Round 1
// baseline (239.210 us; speedup 1.0000x reference)
//
#include <hip/hip_runtime.h>
#include <hip/hip_bf16.h>
#include <stdint.h>
#include <stddef.h>

// HoloLinear: out[b,s,o] = sum_h (sum_i x[b,s,i]*basis[h,i]) * (amp[o,h]*cos(phase[o,h]))
// Factored two-stage bf16 MFMA pipeline:
//   resonance[16384,256] = x_bf16[16384,2048] @ basis_bf16[256,2048]^T
//   out[16384,8192]      = resonance_bf16 @ wreal_bf16[8192,256]^T
//
// Both GEMMs: B^T layout (rows = output cols, k contiguous), m97-style 128x128
// tile, BK=32, 4 waves, global_load_lds width-16 staging, mfma_f32_16x16x32_bf16.

typedef __bf16 bf16x8 __attribute__((ext_vector_type(8)));
typedef float  f32x4  __attribute__((ext_vector_type(8/2)));   // 4 floats
typedef unsigned short u16x8 __attribute__((ext_vector_type(8)));

#define M_ROWS 16384
#define K_IN   2048
#define N_OUT  8192
#define N_HARM 256

__device__ inline unsigned short f2bf(float f) {
    union { float f; uint32_t u; } c; c.f = f;
    uint32_t u = c.u;
    uint32_t r = (u + 0x7fffu + ((u >> 16) & 1u)) >> 16;  // RNE
    return (unsigned short)r;
}

// ---- fp32 -> bf16 conversion, 8 elements/thread ----
__global__ __launch_bounds__(256) void cvt_bf16(const float* __restrict__ in,
                                                unsigned short* __restrict__ out) {
    size_t i = ((size_t)blockIdx.x * 256 + threadIdx.x) * 8;
    float4 v0 = *(const float4*)(in + i);
    float4 v1 = *(const float4*)(in + i + 4);
    u16x8 o;
    o[0] = f2bf(v0.x); o[1] = f2bf(v0.y); o[2] = f2bf(v0.z); o[3] = f2bf(v0.w);
    o[4] = f2bf(v1.x); o[5] = f2bf(v1.y); o[6] = f2bf(v1.z); o[7] = f2bf(v1.w);
    *(u16x8*)(out + i) = o;
}

// ---- w_real = amp * cos(phase) -> bf16, 8 elements/thread ----
__global__ __launch_bounds__(256) void wreal_bf16(const float* __restrict__ phase,
                                                  const float* __restrict__ amp,
                                                  unsigned short* __restrict__ out) {
    size_t i = ((size_t)blockIdx.x * 256 + threadIdx.x) * 8;
    float4 p0 = *(const float4*)(phase + i);
    float4 p1 = *(const float4*)(phase + i + 4);
    float4 a0 = *(const float4*)(amp + i);
    float4 a1 = *(const float4*)(amp + i + 4);
    u16x8 o;
    o[0] = f2bf(a0.x * cosf(p0.x)); o[1] = f2bf(a0.y * cosf(p0.y));
    o[2] = f2bf(a0.z * cosf(p0.z)); o[3] = f2bf(a0.w * cosf(p0.w));
    o[4] = f2bf(a1.x * cosf(p1.x)); o[5] = f2bf(a1.y * cosf(p1.y));
    o[6] = f2bf(a1.z * cosf(p1.z)); o[7] = f2bf(a1.w * cosf(p1.w));
    *(u16x8*)(out + i) = o;
}

// ---- C[M][NCOLS] = A[M][K] @ B[NCOLS][K]^T   (bf16 in, fp32 acc) ----
// 128x128 tile, BK=32, 256 threads = 4 waves (2x2 of 64x64), 16x16x32 MFMA.
template<int K, int NCOLS, bool OUT_BF16>
__global__ __launch_bounds__(256) void gemm_bt(const unsigned short* __restrict__ A,
                                               const unsigned short* __restrict__ B,
                                               void* __restrict__ Cv) {
    __shared__ unsigned short As[128 * 32];
    __shared__ unsigned short Bs[128 * 32];

    const int tid  = threadIdx.x;
    const int lane = tid & 63;
    const int wv   = tid >> 6;
    const int wr   = wv >> 1;   // wave row 0..1
    const int wc   = wv & 1;    // wave col 0..1
    const int bm0  = blockIdx.y * 128;
    const int bn0  = blockIdx.x * 128;

    // staging geometry: thread t loads 8 bf16 (16B); 256 threads cover 64 rows x 32 cols
    const int srow = tid >> 2;          // 0..63
    const int scol = (tid & 3) * 8;     // 0,8,16,24
    const unsigned short* gA0 = A + (size_t)(bm0 + srow) * K + scol;
    const unsigned short* gA1 = gA0 + (size_t)64 * K;
    const unsigned short* gB0 = B + (size_t)(bn0 + srow) * K + scol;
    const unsigned short* gB1 = gB0 + (size_t)64 * K;
    // LDS dest: wave-uniform base + lane*16B (linear layout [row][32])
    unsigned short* lA0 = As + wv * 512;
    unsigned short* lA1 = As + 2048 + wv * 512;
    unsigned short* lB0 = Bs + wv * 512;
    unsigned short* lB1 = Bs + 2048 + wv * 512;

    f32x4 acc[4][4];
#pragma unroll
    for (int i = 0; i < 4; ++i)
#pragma unroll
        for (int j = 0; j < 4; ++j) acc[i][j] = (f32x4){0.f, 0.f, 0.f, 0.f};

    const int frow = lane & 15;         // fragment row (A) / col (B)
    const int kseg = (lane >> 4) * 8;   // contiguous 8-k segment per 16-lane group

    for (int k0 = 0; k0 < K; k0 += 32) {
        __syncthreads();
        __builtin_amdgcn_global_load_lds((const __attribute__((address_space(1))) void*)(gA0 + k0),
                                         (__attribute__((address_space(3))) void*)lA0, 16, 0, 0);
        __builtin_amdgcn_global_load_lds((const __attribute__((address_space(1))) void*)(gA1 + k0),
                                         (__attribute__((address_space(3))) void*)lA1, 16, 0, 0);
        __builtin_amdgcn_global_load_lds((const __attribute__((address_space(1))) void*)(gB0 + k0),
                                         (__attribute__((address_space(3))) void*)lB0, 16, 0, 0);
        __builtin_amdgcn_global_load_lds((const __attribute__((address_space(1))) void*)(gB1 + k0),
                                         (__attribute__((address_space(3))) void*)lB1, 16, 0, 0);
        __syncthreads();

        bf16x8 af[4], bfr[4];
#pragma unroll
        for (int i = 0; i < 4; ++i) {
            af[i]  = *(const bf16x8*)(&As[(wr * 64 + i * 16 + frow) * 32 + kseg]);
            bfr[i] = *(const bf16x8*)(&Bs[(wc * 64 + i * 16 + frow) * 32 + kseg]);
        }
#pragma unroll
        for (int i = 0; i < 4; ++i)
#pragma unroll
            for (int j = 0; j < 4; ++j)
                acc[i][j] = __builtin_amdgcn_mfma_f32_16x16x32_bf16(af[i], bfr[j], acc[i][j], 0, 0, 0);
    }

    // epilogue: C/D layout col = lane&15, row = (lane>>4)*4 + r
#pragma unroll
    for (int i = 0; i < 4; ++i) {
#pragma unroll
        for (int j = 0; j < 4; ++j) {
#pragma unroll
            for (int r = 0; r < 4; ++r) {
                int row = bm0 + wr * 64 + i * 16 + (lane >> 4) * 4 + r;
                int col = bn0 + wc * 64 + j * 16 + (lane & 15);
                if constexpr (OUT_BF16)
                    ((unsigned short*)Cv)[(size_t)row * NCOLS + col] = f2bf(acc[i][j][r]);
                else
                    ((float*)Cv)[(size_t)row * NCOLS + col] = acc[i][j][r];
            }
        }
    }
}

extern "C" void kernel_launch(void* const* d_in, const int* in_sizes, int n_in,
                              void* d_out, int out_size, void* d_ws, size_t ws_size,
                              hipStream_t stream) {
    const float* x     = (const float*)d_in[0];   // [4,4096,2048]
    const float* basis = (const float*)d_in[1];   // [256,2048]
    const float* phase = (const float*)d_in[2];   // [8192,256]
    const float* amp   = (const float*)d_in[3];   // [8192,256]
    float* out = (float*)d_out;                   // [4,4096,8192] fp32

    char* ws = (char*)d_ws;
    unsigned short* xb  = (unsigned short*)(ws);              // x bf16:      67108864 B
    unsigned short* bb  = (unsigned short*)(ws + 67108864);   // basis bf16:   1048576 B
    unsigned short* wrb = (unsigned short*)(ws + 68157440);   // wreal bf16:   4194304 B
    unsigned short* rb  = (unsigned short*)(ws + 72351744);   // resonance:    8388608 B

    // x: 16384*2048 = 33554432 elems -> /8/256 = 16384 blocks
    cvt_bf16<<<dim3(16384), dim3(256), 0, stream>>>(x, xb);
    // basis: 256*2048 = 524288 elems -> 256 blocks
    cvt_bf16<<<dim3(256), dim3(256), 0, stream>>>(basis, bb);
    // wreal: 8192*256 = 2097152 elems -> 1024 blocks
    wreal_bf16<<<dim3(1024), dim3(256), 0, stream>>>(phase, amp, wrb);

    // resonance[16384,256] = xb @ bb^T   (K=2048, N=256)
    gemm_bt<2048, 256, true><<<dim3(256 / 128, M_ROWS / 128), 256, 0, stream>>>(xb, bb, (void*)rb);
    // out[16384,8192] = rb @ wrb^T       (K=256, N=8192)
    gemm_bt<256, 8192, false><<<dim3(N_OUT / 128, M_ROWS / 128), 256, 0, stream>>>(rb, wrb, (void*)out);
}